// Round 6
// baseline (769.207 us; speedup 1.0000x reference)
//
#include <hip/hip_runtime.h>

typedef short short8_t __attribute__((ext_vector_type(8)));
typedef float f32x4 __attribute__((ext_vector_type(4)));

constexpr int B_ = 4, S_ = 2048, HID_ = 1024, E_ = 4, D_ = 256;

__device__ __forceinline__ unsigned short f2bf(float f) {
  unsigned int u = __float_as_uint(f);
  u += 0x7FFFu + ((u >> 16) & 1u);   // RNE
  return (unsigned short)(u >> 16);
}

// hidden [B][S][HID] f32 -> He bf16 [E][B][S][D]
__global__ __launch_bounds__(256) void prep_he(const float* __restrict__ hid,
                                               unsigned short* __restrict__ he) {
  int f = (blockIdx.x * 256 + threadIdx.x) * 4;
  int h = f & (HID_ - 1);
  int s = (f >> 10) & (S_ - 1);
  int b = f >> 21;
  int e = h >> 8, d = h & (D_ - 1);
  float4 v = *(const float4*)(hid + f);
  ushort4 o;
  o.x = f2bf(v.x); o.y = f2bf(v.y); o.z = f2bf(v.z); o.w = f2bf(v.w);
  *(ushort4*)(he + ((((size_t)e * B_ + b) * S_ + s) * D_ + d)) = o;
}

// o_w f32 [HID][HID] -> bf16 copy (row-major [n][k], exactly what B-staging wants)
__global__ __launch_bounds__(256) void prep_ow(const float* __restrict__ w,
                                               unsigned short* __restrict__ o) {
  int f = (blockIdx.x * 256 + threadIdx.x) * 4;
  float4 v = *(const float4*)(w + f);
  ushort4 u;
  u.x = f2bf(v.x); u.y = f2bf(v.y); u.z = f2bf(v.z); u.w = f2bf(v.w);
  *(ushort4*)(o + f) = u;
}

// He [EB][S][D] -> HeT [EB][D][S]  (64x64 LDS tile transpose)
__global__ __launch_bounds__(256) void transpose_he(const unsigned short* __restrict__ he,
                                                    unsigned short* __restrict__ het) {
  const int bid = blockIdx.x;
  const int dt = bid & 3, st = (bid >> 2) & 31, eb = bid >> 7;
  __shared__ unsigned short tile[64][68];
  const int tid = threadIdx.x;
  const unsigned short* src = he + ((size_t)eb * S_ + st * 64) * D_ + dt * 64;
#pragma unroll
  for (int q = 0; q < 4; ++q) {
    int idx = q * 256 + tid;
    int r = idx >> 4, c = (idx & 15) << 2;
    *(ushort4*)&tile[r][c] = *(const ushort4*)(src + (size_t)r * D_ + c);
  }
  __syncthreads();
  unsigned short* dst = het + ((size_t)eb * D_ + dt * 64) * S_ + st * 64;
#pragma unroll
  for (int q = 0; q < 4; ++q) {
    int idx = q * 256 + tid;
    int r = idx >> 4, c = (idx & 15) << 2;  // r = d-local, c = s-local base
    ushort4 o;
    o.x = tile[c + 0][r]; o.y = tile[c + 1][r];
    o.z = tile[c + 2][r]; o.w = tile[c + 3][r];
    *(ushort4*)(dst + (size_t)r * S_ + c) = o;
  }
}

// grouped masked conv1d (fp32) -> key bf16 stored [E][B][t][d]
// out channel d (= g*64+dg) uses input channels g*64..g*64+63, taps k in [g, 8-g]
__global__ __launch_bounds__(256) void conv_kernel(const float* __restrict__ hid,
                                                   const float* __restrict__ cw,
                                                   const float* __restrict__ cb,
                                                   unsigned short* __restrict__ ktd) {
  const int bid = blockIdx.x;
  const int tt = bid & 15, g = (bid >> 4) & 3, b = (bid >> 6) & 3, e = bid >> 8;
  __shared__ float xs[64][136];  // [in-ch][t-window], window = 128 + 8 halo
  const int tid = threadIdx.x;
  for (int idx = tid; idx < 64 * 136; idx += 256) {
    int i = idx & 63, j = idx >> 6;
    int t = tt * 128 + j - 4;
    float v = 0.f;
    if (t >= 0 && t < S_) v = hid[((size_t)b * S_ + t) * HID_ + e * D_ + g * 64 + i];
    xs[i][j] = v;
  }
  __syncthreads();
  const int w = tid >> 6, dg = tid & 63;
  const int tb = w * 32;  // this thread covers 32 t values
  float acc[32];
  const float bias = cb[e * D_ + g * 64 + dg];
#pragma unroll
  for (int q = 0; q < 32; ++q) acc[q] = bias;
  const float* wp0 = cw + (size_t)(e * D_ + g * 64 + dg) * (64 * 9);
  for (int i = 0; i < 64; ++i) {
    const float* wp = wp0 + i * 9;
    float w9[9];
#pragma unroll
    for (int k = 0; k < 9; ++k) w9[k] = ((k >= g) && (k <= 8 - g)) ? wp[k] : 0.f;
#pragma unroll
    for (int tc = 0; tc < 2; ++tc) {
      float win[24];
#pragma unroll
      for (int q = 0; q < 6; ++q)
        *(float4*)&win[q * 4] = *(const float4*)&xs[i][tb + tc * 16 + q * 4];
#pragma unroll
      for (int jj = 0; jj < 16; ++jj) {
        float s = 0.f;
#pragma unroll
        for (int k = 0; k < 9; ++k) s = fmaf(w9[k], win[jj + k], s);
        acc[tc * 16 + jj] += s;
      }
    }
  }
#pragma unroll
  for (int q = 0; q < 32; ++q) {
    int t = tt * 128 + tb + q;
    ktd[(((size_t)e * B_ + b) * S_ + t) * D_ + g * 64 + dg] = f2bf(acc[q]);
  }
}

// C[m][n] = (sum_k A[m][k]*Bm[n][k]) * scale + extra[n]
// A row-major [M][KD] bf16, Bm row-major [N][KD] bf16 (i.e. B^T layout), C fp32 ld=ldc.
// batch via blockIdx.z with element strides sA/sB/sC; extra base + (z&ebmask)*estride.
__global__ __launch_bounds__(256) void gemm_bt(const unsigned short* __restrict__ A,
                                               const unsigned short* __restrict__ Bm,
                                               float* __restrict__ C,
                                               const float* __restrict__ extra,
                                               int KD, int ldc, float scale,
                                               size_t sA, size_t sB, size_t sC,
                                               int ebmask, int estride) {
  const int z = blockIdx.z;
  A += (size_t)z * sA;
  Bm += (size_t)z * sB;
  C += (size_t)z * sC;
  const float* ext = extra + (size_t)(z & ebmask) * estride;
  const int tid = threadIdx.x;
  const int lane = tid & 63, wid = tid >> 6;
  const int wm = wid >> 1, wn = wid & 1;
  const int m0 = blockIdx.y * 128, n0 = blockIdx.x * 128;
  const int l15 = lane & 15, lhi = lane >> 4;
  __shared__ __align__(16) unsigned short As[128 * 32];
  __shared__ __align__(16) unsigned short Bs[128 * 32];
  f32x4 acc[4][4];
  const f32x4 zf = {0.f, 0.f, 0.f, 0.f};
#pragma unroll
  for (int m = 0; m < 4; ++m)
#pragma unroll
    for (int n = 0; n < 4; ++n) acc[m][n] = zf;
  for (int kt = 0; kt < KD; kt += 32) {
    short8_t av[2], bv[2];
#pragma unroll
    for (int c = 0; c < 2; ++c) {
      int idx = c * 256 + tid;
      int row = idx >> 2, col = (idx & 3) << 3;
      av[c] = *(const short8_t*)(A + (size_t)(m0 + row) * KD + kt + col);
      bv[c] = *(const short8_t*)(Bm + (size_t)(n0 + row) * KD + kt + col);
    }
    __syncthreads();
#pragma unroll
    for (int c = 0; c < 2; ++c) {
      int idx = c * 256 + tid;
      int row = idx >> 2, col = (idx & 3) << 3;
      *(short8_t*)&As[row * 32 + col] = av[c];
      *(short8_t*)&Bs[row * 32 + col] = bv[c];
    }
    __syncthreads();
    short8_t af[4], bfr[4];
#pragma unroll
    for (int m = 0; m < 4; ++m)
      af[m] = *(const short8_t*)&As[(wm * 64 + m * 16 + l15) * 32 + (lhi << 3)];
#pragma unroll
    for (int n = 0; n < 4; ++n)
      bfr[n] = *(const short8_t*)&Bs[(wn * 64 + n * 16 + l15) * 32 + (lhi << 3)];
#pragma unroll
    for (int m = 0; m < 4; ++m)
#pragma unroll
      for (int n = 0; n < 4; ++n)
        acc[m][n] = __builtin_amdgcn_mfma_f32_16x16x32_bf16(af[m], bfr[n], acc[m][n], 0, 0, 0);
  }
  const int rbase = m0 + wm * 64 + (lhi << 2);
  const int cbase = n0 + wn * 64 + l15;
  float extv[4];
#pragma unroll
  for (int n = 0; n < 4; ++n) extv[n] = ext[cbase + n * 16];
#pragma unroll
  for (int m = 0; m < 4; ++m) {
#pragma unroll
    for (int r = 0; r < 4; ++r) {
      float* crow = C + (size_t)(rbase + m * 16 + r) * ldc;
#pragma unroll
      for (int n = 0; n < 4; ++n)
        crow[cbase + n * 16] = acc[m][n][r] * scale + extv[n];
    }
  }
}

// per-row max and 1/sum(exp) over scores rows; one wave per row
__global__ __launch_bounds__(256) void softmax_stats(const float* __restrict__ sc,
                                                     float* __restrict__ rmax,
                                                     float* __restrict__ rinv) {
  const int wid = threadIdx.x >> 6, lane = threadIdx.x & 63;
  const size_t row = (size_t)blockIdx.x * 4 + wid;
  const float* p = sc + row * S_;
  float4 v[8];
  float mx = -3.4e38f;
#pragma unroll
  for (int q = 0; q < 8; ++q) {
    v[q] = *(const float4*)(p + q * 256 + lane * 4);
    mx = fmaxf(mx, fmaxf(fmaxf(v[q].x, v[q].y), fmaxf(v[q].z, v[q].w)));
  }
#pragma unroll
  for (int o = 32; o; o >>= 1) mx = fmaxf(mx, __shfl_xor(mx, o));
  float sm = 0.f;
#pragma unroll
  for (int q = 0; q < 8; ++q) {
    sm += __expf(v[q].x - mx); sm += __expf(v[q].y - mx);
    sm += __expf(v[q].z - mx); sm += __expf(v[q].w - mx);
  }
#pragma unroll
  for (int o = 32; o; o >>= 1) sm += __shfl_xor(sm, o);
  if (lane == 0) { rmax[row] = mx; rinv[row] = 1.f / sm; }
}

// ctx[b][s][e*256+d] = (1/sum) * sum_t exp(sc[s][t]-max[s]) * He[t][d]
__global__ __launch_bounds__(256) void pv_kernel(const float* __restrict__ sc,
                                                 const unsigned short* __restrict__ HeT,
                                                 const float* __restrict__ rmax,
                                                 const float* __restrict__ rinv,
                                                 unsigned short* __restrict__ ctx) {
  const int z = blockIdx.z;  // eb
  const int e = z >> 2, b = z & 3;
  const float* Sc = sc + (size_t)z * S_ * S_;
  const unsigned short* Bg = HeT + (size_t)z * D_ * S_;
  const float* rmx = rmax + (size_t)z * S_;
  const float* rin = rinv + (size_t)z * S_;
  const int tid = threadIdx.x;
  const int lane = tid & 63, wid = tid >> 6;
  const int wm = wid >> 1, wn = wid & 1;
  const int m0 = blockIdx.y * 128, n0 = blockIdx.x * 128;
  const int l15 = lane & 15, lhi = lane >> 4;
  __shared__ __align__(16) unsigned short As[128 * 64];  // P bf16 [s][t]
  __shared__ __align__(16) unsigned short Bs[128 * 64];  // He^T bf16 [d][t]
  f32x4 acc[4][4];
  const f32x4 zf = {0.f, 0.f, 0.f, 0.f};
#pragma unroll
  for (int m = 0; m < 4; ++m)
#pragma unroll
    for (int n = 0; n < 4; ++n) acc[m][n] = zf;
  for (int kt = 0; kt < S_; kt += 64) {
    ushort4 pa[8];
#pragma unroll
    for (int q = 0; q < 8; ++q) {
      int idx = q * 256 + tid;
      int row = idx >> 4, c4 = (idx & 15) << 2;
      float4 vv = *(const float4*)(Sc + (size_t)(m0 + row) * S_ + kt + c4);
      float mrow = rmx[m0 + row];
      pa[q].x = f2bf(__expf(vv.x - mrow));
      pa[q].y = f2bf(__expf(vv.y - mrow));
      pa[q].z = f2bf(__expf(vv.z - mrow));
      pa[q].w = f2bf(__expf(vv.w - mrow));
    }
    short8_t bv[4];
#pragma unroll
    for (int c = 0; c < 4; ++c) {
      int idx = c * 256 + tid;
      int row = idx >> 3, col = (idx & 7) << 3;
      bv[c] = *(const short8_t*)(Bg + (size_t)(n0 + row) * S_ + kt + col);
    }
    __syncthreads();
#pragma unroll
    for (int q = 0; q < 8; ++q) {
      int idx = q * 256 + tid;
      int row = idx >> 4, c4 = (idx & 15) << 2;
      *(ushort4*)&As[row * 64 + c4] = pa[q];
    }
#pragma unroll
    for (int c = 0; c < 4; ++c) {
      int idx = c * 256 + tid;
      int row = idx >> 3, col = (idx & 7) << 3;
      *(short8_t*)&Bs[row * 64 + col] = bv[c];
    }
    __syncthreads();
    short8_t af[2][4], bfr[2][4];
#pragma unroll
    for (int kk = 0; kk < 2; ++kk) {
#pragma unroll
      for (int m = 0; m < 4; ++m)
        af[kk][m] = *(const short8_t*)&As[(wm * 64 + m * 16 + l15) * 64 + kk * 32 + (lhi << 3)];
#pragma unroll
      for (int n = 0; n < 4; ++n)
        bfr[kk][n] = *(const short8_t*)&Bs[(wn * 64 + n * 16 + l15) * 64 + kk * 32 + (lhi << 3)];
    }
#pragma unroll
    for (int kk = 0; kk < 2; ++kk)
#pragma unroll
      for (int m = 0; m < 4; ++m)
#pragma unroll
        for (int n = 0; n < 4; ++n)
          acc[m][n] = __builtin_amdgcn_mfma_f32_16x16x32_bf16(af[kk][m], bfr[kk][n], acc[m][n], 0, 0, 0);
  }
  const int rb = m0 + wm * 64 + (lhi << 2);
  const int cb = n0 + wn * 64 + l15;
#pragma unroll
  for (int m = 0; m < 4; ++m)
#pragma unroll
    for (int r = 0; r < 4; ++r) {
      int row = rb + m * 16 + r;
      float ri = rin[row];
#pragma unroll
      for (int n = 0; n < 4; ++n)
        ctx[((size_t)b * S_ + row) * HID_ + e * D_ + cb + n * 16] = f2bf(acc[m][n][r] * ri);
    }
}

extern "C" void kernel_launch(void* const* d_in, const int* in_sizes, int n_in,
                              void* d_out, int out_size, void* d_ws, size_t ws_size,
                              hipStream_t stream) {
  const float* hidden = (const float*)d_in[0];
  const float* amask  = (const float*)d_in[1];
  const float* conv_w = (const float*)d_in[2];
  const float* conv_b = (const float*)d_in[3];
  const float* o_w    = (const float*)d_in[4];
  const float* o_b    = (const float*)d_in[5];

  float* out = (float*)d_out;                               // [B][S][HID]
  float* scores = out + (size_t)B_ * S_ * HID_;             // [E][B][S][S]

  char* ws = (char*)d_ws;
  size_t off = 0;
  auto carve = [&](size_t bytes) {
    void* p = ws + off;
    off += (bytes + 255) & ~(size_t)255;
    return p;
  };
  const size_t NE = (size_t)E_ * B_ * S_ * D_;              // 8388608
  unsigned short* He  = (unsigned short*)carve(NE * 2);     // [EB][S][D]
  unsigned short* HeT = (unsigned short*)carve(NE * 2);     // [EB][D][S]
  unsigned short* Ktd = (unsigned short*)carve(NE * 2);     // [EB][S(t)][D]
  unsigned short* OwB = (unsigned short*)carve((size_t)HID_ * HID_ * 2);
  unsigned short* Ctx = (unsigned short*)carve(NE * 2);     // [B][S][HID]
  float* rmax = (float*)carve((size_t)E_ * B_ * S_ * 4);
  float* rinv = (float*)carve((size_t)E_ * B_ * S_ * 4);

  prep_he<<<8192, 256, 0, stream>>>(hidden, He);
  prep_ow<<<1024, 256, 0, stream>>>(o_w, OwB);
  transpose_he<<<2048, 256, 0, stream>>>(He, HeT);
  conv_kernel<<<1024, 256, 0, stream>>>(hidden, conv_w, conv_b, Ktd);

  // scores[eb][s][t] = (He . Ktd) * 1/16 + mask[b][t]
  gemm_bt<<<dim3(16, 16, 16), 256, 0, stream>>>(
      He, Ktd, scores, amask, D_, S_, 0.0625f,
      (size_t)S_ * D_, (size_t)S_ * D_, (size_t)S_ * S_, 3, S_);

  softmax_stats<<<8192, 256, 0, stream>>>(scores, rmax, rinv);
  pv_kernel<<<dim3(2, 16, 16), 256, 0, stream>>>(scores, HeT, rmax, rinv, Ctx);

  // out[bs][h] = Ctx . OwB^T + o_b
  gemm_bt<<<dim3(8, 64, 1), 256, 0, stream>>>(
      Ctx, OwB, out, o_b, HID_, HID_, 1.0f, 0, 0, 0, 0, 0);
}

// Round 7
// 745.494 us; speedup vs baseline: 1.0318x; 1.0318x over previous
//
#include <hip/hip_runtime.h>

typedef short short8_t __attribute__((ext_vector_type(8)));
typedef float f32x4 __attribute__((ext_vector_type(4)));

constexpr int B_ = 4, S_ = 2048, HID_ = 1024, E_ = 4, D_ = 256;

__device__ __forceinline__ unsigned short f2bf(float f) {
  unsigned int u = __float_as_uint(f);
  u += 0x7FFFu + ((u >> 16) & 1u);   // RNE
  return (unsigned short)(u >> 16);
}

// hidden [B][S][HID] f32 -> He bf16 [E][B][S][D]
__global__ __launch_bounds__(256) void prep_he(const float* __restrict__ hid,
                                               unsigned short* __restrict__ he) {
  int f = (blockIdx.x * 256 + threadIdx.x) * 4;
  int h = f & (HID_ - 1);
  int s = (f >> 10) & (S_ - 1);
  int b = f >> 21;
  int e = h >> 8, d = h & (D_ - 1);
  float4 v = *(const float4*)(hid + f);
  ushort4 o;
  o.x = f2bf(v.x); o.y = f2bf(v.y); o.z = f2bf(v.z); o.w = f2bf(v.w);
  *(ushort4*)(he + ((((size_t)e * B_ + b) * S_ + s) * D_ + d)) = o;
}

// o_w f32 [HID][HID] -> bf16 copy (row-major [n][k], exactly what B-staging wants)
__global__ __launch_bounds__(256) void prep_ow(const float* __restrict__ w,
                                               unsigned short* __restrict__ o) {
  int f = (blockIdx.x * 256 + threadIdx.x) * 4;
  float4 v = *(const float4*)(w + f);
  ushort4 u;
  u.x = f2bf(v.x); u.y = f2bf(v.y); u.z = f2bf(v.z); u.w = f2bf(v.w);
  *(ushort4*)(o + f) = u;
}

// conv_w [E][D_E][64][9] f32 -> wk [e][g][k][i][dg] f32, masked (zero outside [g, 8-g])
// Lane dg then reads CONSECUTIVE addresses in conv -> 1 coalesced load per (i,k) per wave.
__global__ __launch_bounds__(256) void prep_wk(const float* __restrict__ cw,
                                               float* __restrict__ wk) {
  int f = blockIdx.x * 256 + threadIdx.x;   // 589824 total
  int dg = f & 63;
  int i  = (f >> 6) & 63;
  int r  = f >> 12;          // eg*9 + k
  int k  = r % 9;
  int eg = r / 9;
  int e = eg >> 2, g = eg & 3;
  float v = cw[((size_t)((e * 256 + g * 64 + dg) * 64 + i)) * 9 + k];
  if (k < g || k > 8 - g) v = 0.f;
  wk[f] = v;
}

// He [EB][S][D] -> HeT [EB][D][S]  (64x64 LDS tile transpose)
__global__ __launch_bounds__(256) void transpose_he(const unsigned short* __restrict__ he,
                                                    unsigned short* __restrict__ het) {
  const int bid = blockIdx.x;
  const int dt = bid & 3, st = (bid >> 2) & 31, eb = bid >> 7;
  __shared__ unsigned short tile[64][68];
  const int tid = threadIdx.x;
  const unsigned short* src = he + ((size_t)eb * S_ + st * 64) * D_ + dt * 64;
#pragma unroll
  for (int q = 0; q < 4; ++q) {
    int idx = q * 256 + tid;
    int r = idx >> 4, c = (idx & 15) << 2;
    *(ushort4*)&tile[r][c] = *(const ushort4*)(src + (size_t)r * D_ + c);
  }
  __syncthreads();
  unsigned short* dst = het + ((size_t)eb * D_ + dt * 64) * S_ + st * 64;
#pragma unroll
  for (int q = 0; q < 4; ++q) {
    int idx = q * 256 + tid;
    int r = idx >> 4, c = (idx & 15) << 2;  // r = d-local, c = s-local base
    ushort4 o;
    o.x = tile[c + 0][r]; o.y = tile[c + 1][r];
    o.z = tile[c + 2][r]; o.w = tile[c + 3][r];
    *(ushort4*)(dst + (size_t)r * S_ + c) = o;
  }
}

// grouped masked conv1d (fp32) -> key bf16 stored [E][B][t][d]
// out channel d (= g*64+dg) uses input channels g*64..g*64+63, taps k in [g, 8-g]
// v2: weights read coalesced from wk[e][g][k][i][dg]; wave-uniform tap bounds.
__global__ __launch_bounds__(256) void conv_kernel(const float* __restrict__ hid,
                                                   const float* __restrict__ wk,
                                                   const float* __restrict__ cb,
                                                   unsigned short* __restrict__ ktd) {
  const int bid = blockIdx.x;
  const int tt = bid & 15, g = (bid >> 4) & 3, b = (bid >> 6) & 3, e = bid >> 8;
  __shared__ float xs[64][136];  // [in-ch][t-window], window = 128 + 8 halo
  const int tid = threadIdx.x;
  for (int idx = tid; idx < 64 * 136; idx += 256) {
    int i = idx & 63, j = idx >> 6;
    int t = tt * 128 + j - 4;
    float v = 0.f;
    if (t >= 0 && t < S_) v = hid[((size_t)b * S_ + t) * HID_ + e * D_ + g * 64 + i];
    xs[i][j] = v;
  }
  __syncthreads();
  const int w = tid >> 6, dg = tid & 63;
  const int tb = w * 32;  // this thread covers 32 t values
  float acc[32];
  const float bias = cb[e * D_ + g * 64 + dg];
#pragma unroll
  for (int q = 0; q < 32; ++q) acc[q] = bias;
  // wk base for (e,g): [9][64 i][64 dg]
  const float* wkp = wk + (size_t)(e * 4 + g) * (9 * 64 * 64) + dg;
  for (int i = 0; i < 64; ++i) {
    float win[40];
#pragma unroll
    for (int q = 0; q < 10; ++q)
      *(float4*)&win[q * 4] = *(const float4*)&xs[i][tb + q * 4];
#pragma unroll
    for (int k = 0; k < 9; ++k) {
      if (k >= g && k <= 8 - g) {       // wave-uniform (g uniform per block)
        float wv = wkp[(k * 64 + i) * 64];   // coalesced: lane dg -> consecutive 4B
#pragma unroll
        for (int jj = 0; jj < 32; ++jj)
          acc[jj] = fmaf(wv, win[jj + k], acc[jj]);
      }
    }
  }
#pragma unroll
  for (int q = 0; q < 32; ++q) {
    int t = tt * 128 + tb + q;
    ktd[(((size_t)e * B_ + b) * S_ + t) * D_ + g * 64 + dg] = f2bf(acc[q]);
  }
}

// C[m][n] = (sum_k A[m][k]*Bm[n][k]) * scale + extra[n]
// A row-major [M][KD] bf16, Bm row-major [N][KD] bf16 (i.e. B^T layout), C fp32 ld=ldc.
// batch via blockIdx.z with element strides sA/sB/sC; extra base + (z&ebmask)*estride.
__global__ __launch_bounds__(256) void gemm_bt(const unsigned short* __restrict__ A,
                                               const unsigned short* __restrict__ Bm,
                                               float* __restrict__ C,
                                               const float* __restrict__ extra,
                                               int KD, int ldc, float scale,
                                               size_t sA, size_t sB, size_t sC,
                                               int ebmask, int estride) {
  const int z = blockIdx.z;
  A += (size_t)z * sA;
  Bm += (size_t)z * sB;
  C += (size_t)z * sC;
  const float* ext = extra + (size_t)(z & ebmask) * estride;
  const int tid = threadIdx.x;
  const int lane = tid & 63, wid = tid >> 6;
  const int wm = wid >> 1, wn = wid & 1;
  const int m0 = blockIdx.y * 128, n0 = blockIdx.x * 128;
  const int l15 = lane & 15, lhi = lane >> 4;
  __shared__ __align__(16) unsigned short As[128 * 32];
  __shared__ __align__(16) unsigned short Bs[128 * 32];
  f32x4 acc[4][4];
  const f32x4 zf = {0.f, 0.f, 0.f, 0.f};
#pragma unroll
  for (int m = 0; m < 4; ++m)
#pragma unroll
    for (int n = 0; n < 4; ++n) acc[m][n] = zf;
  for (int kt = 0; kt < KD; kt += 32) {
    short8_t av[2], bv[2];
#pragma unroll
    for (int c = 0; c < 2; ++c) {
      int idx = c * 256 + tid;
      int row = idx >> 2, col = (idx & 3) << 3;
      av[c] = *(const short8_t*)(A + (size_t)(m0 + row) * KD + kt + col);
      bv[c] = *(const short8_t*)(Bm + (size_t)(n0 + row) * KD + kt + col);
    }
    __syncthreads();
#pragma unroll
    for (int c = 0; c < 2; ++c) {
      int idx = c * 256 + tid;
      int row = idx >> 2, col = (idx & 3) << 3;
      *(short8_t*)&As[row * 32 + col] = av[c];
      *(short8_t*)&Bs[row * 32 + col] = bv[c];
    }
    __syncthreads();
    short8_t af[4], bfr[4];
#pragma unroll
    for (int m = 0; m < 4; ++m)
      af[m] = *(const short8_t*)&As[(wm * 64 + m * 16 + l15) * 32 + (lhi << 3)];
#pragma unroll
    for (int n = 0; n < 4; ++n)
      bfr[n] = *(const short8_t*)&Bs[(wn * 64 + n * 16 + l15) * 32 + (lhi << 3)];
#pragma unroll
    for (int m = 0; m < 4; ++m)
#pragma unroll
      for (int n = 0; n < 4; ++n)
        acc[m][n] = __builtin_amdgcn_mfma_f32_16x16x32_bf16(af[m], bfr[n], acc[m][n], 0, 0, 0);
  }
  const int rbase = m0 + wm * 64 + (lhi << 2);
  const int cbase = n0 + wn * 64 + l15;
  float extv[4];
#pragma unroll
  for (int n = 0; n < 4; ++n) extv[n] = ext[cbase + n * 16];
#pragma unroll
  for (int m = 0; m < 4; ++m) {
#pragma unroll
    for (int r = 0; r < 4; ++r) {
      float* crow = C + (size_t)(rbase + m * 16 + r) * ldc;
#pragma unroll
      for (int n = 0; n < 4; ++n)
        crow[cbase + n * 16] = acc[m][n][r] * scale + extv[n];
    }
  }
}

// per-row max and 1/sum(exp) over scores rows; one wave per row
__global__ __launch_bounds__(256) void softmax_stats(const float* __restrict__ sc,
                                                     float* __restrict__ rmax,
                                                     float* __restrict__ rinv) {
  const int wid = threadIdx.x >> 6, lane = threadIdx.x & 63;
  const size_t row = (size_t)blockIdx.x * 4 + wid;
  const float* p = sc + row * S_;
  float4 v[8];
  float mx = -3.4e38f;
#pragma unroll
  for (int q = 0; q < 8; ++q) {
    v[q] = *(const float4*)(p + q * 256 + lane * 4);
    mx = fmaxf(mx, fmaxf(fmaxf(v[q].x, v[q].y), fmaxf(v[q].z, v[q].w)));
  }
#pragma unroll
  for (int o = 32; o; o >>= 1) mx = fmaxf(mx, __shfl_xor(mx, o));
  float sm = 0.f;
#pragma unroll
  for (int q = 0; q < 8; ++q) {
    sm += __expf(v[q].x - mx); sm += __expf(v[q].y - mx);
    sm += __expf(v[q].z - mx); sm += __expf(v[q].w - mx);
  }
#pragma unroll
  for (int o = 32; o; o >>= 1) sm += __shfl_xor(sm, o);
  if (lane == 0) { rmax[row] = mx; rinv[row] = 1.f / sm; }
}

// ctx[b][s][e*256+d] = (1/sum) * sum_t exp(sc[s][t]-max[s]) * He[t][d]
__global__ __launch_bounds__(256) void pv_kernel(const float* __restrict__ sc,
                                                 const unsigned short* __restrict__ HeT,
                                                 const float* __restrict__ rmax,
                                                 const float* __restrict__ rinv,
                                                 unsigned short* __restrict__ ctx) {
  const int z = blockIdx.z;  // eb
  const int e = z >> 2, b = z & 3;
  const float* Sc = sc + (size_t)z * S_ * S_;
  const unsigned short* Bg = HeT + (size_t)z * D_ * S_;
  const float* rmx = rmax + (size_t)z * S_;
  const float* rin = rinv + (size_t)z * S_;
  const int tid = threadIdx.x;
  const int lane = tid & 63, wid = tid >> 6;
  const int wm = wid >> 1, wn = wid & 1;
  const int m0 = blockIdx.y * 128, n0 = blockIdx.x * 128;
  const int l15 = lane & 15, lhi = lane >> 4;
  __shared__ __align__(16) unsigned short As[128 * 64];  // P bf16 [s][t]
  __shared__ __align__(16) unsigned short Bs[128 * 64];  // He^T bf16 [d][t]
  f32x4 acc[4][4];
  const f32x4 zf = {0.f, 0.f, 0.f, 0.f};
#pragma unroll
  for (int m = 0; m < 4; ++m)
#pragma unroll
    for (int n = 0; n < 4; ++n) acc[m][n] = zf;
  for (int kt = 0; kt < S_; kt += 64) {
    ushort4 pa[8];
#pragma unroll
    for (int q = 0; q < 8; ++q) {
      int idx = q * 256 + tid;
      int row = idx >> 4, c4 = (idx & 15) << 2;
      float4 vv = *(const float4*)(Sc + (size_t)(m0 + row) * S_ + kt + c4);
      float mrow = rmx[m0 + row];
      pa[q].x = f2bf(__expf(vv.x - mrow));
      pa[q].y = f2bf(__expf(vv.y - mrow));
      pa[q].z = f2bf(__expf(vv.z - mrow));
      pa[q].w = f2bf(__expf(vv.w - mrow));
    }
    short8_t bv[4];
#pragma unroll
    for (int c = 0; c < 4; ++c) {
      int idx = c * 256 + tid;
      int row = idx >> 3, col = (idx & 7) << 3;
      bv[c] = *(const short8_t*)(Bg + (size_t)(n0 + row) * S_ + kt + col);
    }
    __syncthreads();
#pragma unroll
    for (int q = 0; q < 8; ++q) {
      int idx = q * 256 + tid;
      int row = idx >> 4, c4 = (idx & 15) << 2;
      *(ushort4*)&As[row * 64 + c4] = pa[q];
    }
#pragma unroll
    for (int c = 0; c < 4; ++c) {
      int idx = c * 256 + tid;
      int row = idx >> 3, col = (idx & 7) << 3;
      *(short8_t*)&Bs[row * 64 + col] = bv[c];
    }
    __syncthreads();
    short8_t af[2][4], bfr[2][4];
#pragma unroll
    for (int kk = 0; kk < 2; ++kk) {
#pragma unroll
      for (int m = 0; m < 4; ++m)
        af[kk][m] = *(const short8_t*)&As[(wm * 64 + m * 16 + l15) * 64 + kk * 32 + (lhi << 3)];
#pragma unroll
      for (int n = 0; n < 4; ++n)
        bfr[kk][n] = *(const short8_t*)&Bs[(wn * 64 + n * 16 + l15) * 64 + kk * 32 + (lhi << 3)];
    }
#pragma unroll
    for (int kk = 0; kk < 2; ++kk)
#pragma unroll
      for (int m = 0; m < 4; ++m)
#pragma unroll
        for (int n = 0; n < 4; ++n)
          acc[m][n] = __builtin_amdgcn_mfma_f32_16x16x32_bf16(af[kk][m], bfr[kk][n], acc[m][n], 0, 0, 0);
  }
  const int rb = m0 + wm * 64 + (lhi << 2);
  const int cb = n0 + wn * 64 + l15;
#pragma unroll
  for (int m = 0; m < 4; ++m)
#pragma unroll
    for (int r = 0; r < 4; ++r) {
      int row = rb + m * 16 + r;
      float ri = rin[row];
#pragma unroll
      for (int n = 0; n < 4; ++n)
        ctx[((size_t)b * S_ + row) * HID_ + e * D_ + cb + n * 16] = f2bf(acc[m][n][r] * ri);
    }
}

extern "C" void kernel_launch(void* const* d_in, const int* in_sizes, int n_in,
                              void* d_out, int out_size, void* d_ws, size_t ws_size,
                              hipStream_t stream) {
  const float* hidden = (const float*)d_in[0];
  const float* amask  = (const float*)d_in[1];
  const float* conv_w = (const float*)d_in[2];
  const float* conv_b = (const float*)d_in[3];
  const float* o_w    = (const float*)d_in[4];
  const float* o_b    = (const float*)d_in[5];

  float* out = (float*)d_out;                               // [B][S][HID]
  float* scores = out + (size_t)B_ * S_ * HID_;             // [E][B][S][S]

  char* ws = (char*)d_ws;
  size_t off = 0;
  auto carve = [&](size_t bytes) {
    void* p = ws + off;
    off += (bytes + 255) & ~(size_t)255;
    return p;
  };
  const size_t NE = (size_t)E_ * B_ * S_ * D_;              // 8388608
  unsigned short* He  = (unsigned short*)carve(NE * 2);     // [EB][S][D]
  unsigned short* HeT = (unsigned short*)carve(NE * 2);     // [EB][D][S]
  unsigned short* Ktd = (unsigned short*)carve(NE * 2);     // [EB][S(t)][D]
  unsigned short* OwB = (unsigned short*)carve((size_t)HID_ * HID_ * 2);
  unsigned short* Ctx = (unsigned short*)carve(NE * 2);     // [B][S][HID]
  float* rmax = (float*)carve((size_t)E_ * B_ * S_ * 4);
  float* rinv = (float*)carve((size_t)E_ * B_ * S_ * 4);
  float* Wk   = (float*)carve((size_t)E_ * 4 * 9 * 64 * 64 * 4);  // [e][g][k][i][dg]

  prep_he<<<8192, 256, 0, stream>>>(hidden, He);
  prep_ow<<<1024, 256, 0, stream>>>(o_w, OwB);
  prep_wk<<<2304, 256, 0, stream>>>(conv_w, Wk);
  transpose_he<<<2048, 256, 0, stream>>>(He, HeT);
  conv_kernel<<<1024, 256, 0, stream>>>(hidden, Wk, conv_b, Ktd);

  // scores[eb][s][t] = (He . Ktd) * 1/16 + mask[b][t]
  gemm_bt<<<dim3(16, 16, 16), 256, 0, stream>>>(
      He, Ktd, scores, amask, D_, S_, 0.0625f,
      (size_t)S_ * D_, (size_t)S_ * D_, (size_t)S_ * S_, 3, S_);

  softmax_stats<<<8192, 256, 0, stream>>>(scores, rmax, rinv);
  pv_kernel<<<dim3(2, 16, 16), 256, 0, stream>>>(scores, HeT, rmax, rinv, Ctx);

  // out[bs][h] = Ctx . OwB^T + o_b
  gemm_bt<<<dim3(8, 64, 1), 256, 0, stream>>>(
      Ctx, OwB, out, o_b, HID_, HID_, 1.0f, 0, 0, 0, 0, 0);
}